// Round 4
// baseline (406.859 us; speedup 1.0000x reference)
//
#include <hip/hip_runtime.h>
#include <stdint.h>

// SmallMLP: x[65536,784] @ tern(w1[320,784])^T + b1 -> tern -> @ tern(w2[10,320])^T + b2 -> log_softmax
// R4: barrier-free main loop. No LDS staging: A (x, hi/lo bf16 split) and B (pre-tiled tern(w1))
// fragments are loaded straight from global (L1/L2/L3-resident) into registers per 16x16x32 MFMA.
// Wave tile = 32 rows x 320 cols (acc 2x20 f32x4 = 160 AGPRs). Epilogue (tern -> layer2 -> log_softmax)
// unchanged in math from the verified R1, adapted to 32-row wave tiles.

#define TERN_TH 0.001f

using bf16x8 = __attribute__((ext_vector_type(8))) short;   // 8 bf16 = 4 VGPR
using f32x4  = __attribute__((ext_vector_type(4))) float;   // 4 fp32 acc

__device__ __forceinline__ unsigned short f2bf(float f) {
    unsigned u = __float_as_uint(f);
    u = (u + 0x7FFFu + ((u >> 16) & 1u)) >> 16;   // RNE
    return (unsigned short)u;
}
__device__ __forceinline__ float bf2f(unsigned short h) {
    return __uint_as_float(((unsigned)h) << 16);
}
__device__ __forceinline__ float ternf(float w) {
    return (w > TERN_TH) ? 1.0f : ((w < -TERN_TH) ? -1.0f : 0.0f);
}

// Build hi/lo bf16x8 fragments from 8 consecutive floats (two float4)
__device__ __forceinline__ void split8(float4 a, float4 b, bf16x8& hi, bf16x8& lo) {
    float v[8] = {a.x, a.y, a.z, a.w, b.x, b.y, b.z, b.w};
    bf16x8 h, l;
#pragma unroll
    for (int i = 0; i < 8; ++i) {
        unsigned short hh = f2bf(v[i]);
        h[i] = (short)hh;
        l[i] = (short)f2bf(v[i] - bf2f(hh));
    }
    hi = h; lo = l;
}

// ---------------- prep: ternarize w1 -> bf16, B-fragment order:
// q1f[c(25)][nt(20)][quad(4)][col(16)][kk(8)]  (512 KB; one coalesced dwordx4 per wave-frag)
#define Q1F_ELEMS (25 * 20 * 4 * 16 * 8)
__global__ void prep_q1(const float* __restrict__ w1, unsigned short* __restrict__ q1f) {
    int idx = blockIdx.x * 256 + threadIdx.x;
    if (idx >= Q1F_ELEMS) return;
    int kk   = idx & 7;
    int col  = (idx >> 3) & 15;
    int quad = (idx >> 7) & 3;
    int t    = idx >> 9;
    int nt   = t % 20;
    int c    = t / 20;
    int k = c * 32 + quad * 8 + kk;
    int j = nt * 16 + col;
    float v = (k < 784) ? ternf(w1[j * 784 + k]) : 0.0f;
    q1f[idx] = f2bf(v);
}

// ---------------- LDS (epilogue only)
#define LDS_H   0                  // [64][328] bf16 = 41984
#define LDS_Q2  41984              // [16][328] bf16 = 10496 -> total 52480
#define LDS_TOTAL 52480

__global__ __launch_bounds__(256, 2) void mlp_main(
    const float* __restrict__ x, const unsigned short* __restrict__ q1f,
    const float* __restrict__ b1, const float* __restrict__ w2,
    const float* __restrict__ b2, float* __restrict__ out) {

    __shared__ __attribute__((aligned(16))) unsigned char smem[LDS_TOTAL];
    unsigned short* sm16 = (unsigned short*)smem;

    const int tid  = threadIdx.x;
    const int lane = tid & 63;
    const int wave = tid >> 6;     // 4 waves, each owns 32 rows x 320 cols
    const int quad = lane >> 4;
    const int l15  = lane & 15;
    const int blk  = blockIdx.x;   // 512 blocks * 128 rows

    f32x4 acc[2][20];
#pragma unroll
    for (int mt = 0; mt < 2; ++mt)
#pragma unroll
        for (int nt = 0; nt < 20; ++nt) {
            f32x4 z = {0.f, 0.f, 0.f, 0.f};
            acc[mt][nt] = z;
        }

    const int rowbase = blk * 128 + wave * 32;
    const float* xr0 = x + (size_t)(rowbase + l15) * 784;        // mt=0 row for this lane
    const float* xr1 = x + (size_t)(rowbase + 16 + l15) * 784;   // mt=1 row
    // B frag byte address for this lane within a chunk: nt*1024 + quad*256 + l15*16
    const unsigned short* bq1 = q1f + (size_t)quad * 128 + (size_t)l15 * 8;

    for (int c = 0; c < 25; ++c) {
        int kq  = c * 32 + quad * 8;
        int kqs = (kq < 784) ? kq : 0;      // c==24, quad 2/3: clamp (B frag is zero there)

        // A fragments: 8 consecutive floats per lane per mt, hi/lo split in-register
        bf16x8 ahi0, alo0, ahi1, alo1;
        {
            const float4* p0 = (const float4*)(xr0 + kqs);
            const float4* p1 = (const float4*)(xr1 + kqs);
            float4 a0 = p0[0], b0 = p0[1];
            float4 a1 = p1[0], b1_ = p1[1];
            split8(a0, b0, ahi0, alo0);
            split8(a1, b1_, ahi1, alo1);
        }

        const unsigned short* bp = bq1 + (size_t)c * 10240;   // elements
#pragma unroll
        for (int nt = 0; nt < 20; ++nt) {
            bf16x8 bq = *(const bf16x8*)(bp + (size_t)nt * 512);
            acc[0][nt] = __builtin_amdgcn_mfma_f32_16x16x32_bf16(ahi0, bq, acc[0][nt], 0, 0, 0);
            acc[0][nt] = __builtin_amdgcn_mfma_f32_16x16x32_bf16(alo0, bq, acc[0][nt], 0, 0, 0);
            acc[1][nt] = __builtin_amdgcn_mfma_f32_16x16x32_bf16(ahi1, bq, acc[1][nt], 0, 0, 0);
            acc[1][nt] = __builtin_amdgcn_mfma_f32_16x16x32_bf16(alo1, bq, acc[1][nt], 0, 0, 0);
        }
    }

    // ---------------- fused epilogue
    // stage q2: tern(w2) -> bf16 [16][328], rows 10..15 and cols 320..327 zero
    for (int idx = tid; idx < 16 * 328; idx += 256) {
        int o = idx / 328, j = idx % 328;
        float v = (o < 10 && j < 320) ? ternf(w2[o * 320 + j]) : 0.0f;
        sm16[(LDS_Q2 >> 1) + idx] = f2bf(v);
    }
    float b1v[20];
#pragma unroll
    for (int nt = 0; nt < 20; ++nt) b1v[nt] = b1[nt * 16 + l15];
    float b2v = (l15 < 10) ? b2[l15] : 0.0f;

    for (int pass = 0; pass < 2; ++pass) {
        __syncthreads();
        // waves owning this 64-row half write ternarized h (bf16) to LDS
        if ((wave >> 1) == pass) {
#pragma unroll
            for (int mt = 0; mt < 2; ++mt)
#pragma unroll
                for (int nt = 0; nt < 20; ++nt)
#pragma unroll
                    for (int i = 0; i < 4; ++i) {
                        float hv = acc[mt][nt][i] + b1v[nt];
                        int row = (wave & 1) * 32 + mt * 16 + quad * 4 + i;  // C layout: col=lane&15, row=quad*4+reg
                        int col = nt * 16 + l15;
                        sm16[(LDS_H >> 1) + row * 328 + col] = f2bf(ternf(hv));
                    }
        }
        __syncthreads();
        // layer 2: each wave computes 16 rows x 16 cols (10 valid), K=320
        f32x4 acc2 = {0.f, 0.f, 0.f, 0.f};
#pragma unroll
        for (int kc = 0; kc < 10; ++kc) {
            bf16x8 a = *(const bf16x8*)(smem + LDS_H + (wave * 16 + l15) * 656 + kc * 64 + quad * 16);
            bf16x8 b = *(const bf16x8*)(smem + LDS_Q2 + l15 * 656 + kc * 64 + quad * 16);
            acc2 = __builtin_amdgcn_mfma_f32_16x16x32_bf16(a, b, acc2, 0, 0, 0);
        }
        // log_softmax across the 16 lanes holding one row (cols), 10 valid
#pragma unroll
        for (int i = 0; i < 4; ++i) {
            float l  = acc2[i] + b2v;
            float lm = (l15 < 10) ? l : -3.4e38f;
#pragma unroll
            for (int s = 8; s >= 1; s >>= 1) lm = fmaxf(lm, __shfl_xor(lm, s, 64));
            float e  = (l15 < 10) ? expf(l - lm) : 0.0f;
            float ss = e;
#pragma unroll
            for (int s = 8; s >= 1; s >>= 1) ss += __shfl_xor(ss, s, 64);
            float ov = (l - lm) - logf(ss);
            if (l15 < 10) {
                int grow = blk * 128 + pass * 64 + wave * 16 + quad * 4 + i;
                out[(size_t)grow * 10 + l15] = ov;
            }
        }
    }
}

extern "C" void kernel_launch(void* const* d_in, const int* in_sizes, int n_in,
                              void* d_out, int out_size, void* d_ws, size_t ws_size,
                              hipStream_t stream) {
    const float* x  = (const float*)d_in[0];
    const float* w1 = (const float*)d_in[1];
    const float* b1 = (const float*)d_in[2];
    const float* w2 = (const float*)d_in[3];
    const float* b2 = (const float*)d_in[4];
    unsigned short* q1f = (unsigned short*)d_ws;   // 512000 B

    prep_q1<<<(Q1F_ELEMS + 255) / 256, 256, 0, stream>>>(w1, q1f);
    mlp_main<<<512, 256, 0, stream>>>(x, q1f, b1, w2, b2, (float*)d_out);
}

// Round 6
// 369.913 us; speedup vs baseline: 1.0999x; 1.0999x over previous
//
#include <hip/hip_runtime.h>
#include <stdint.h>

// SmallMLP: x[65536,784] @ tern(w1[320,784])^T + b1 -> tern -> @ tern(w2[10,320])^T + b2 -> log_softmax
// R5 hybrid: A (x) raw from global one chunk ahead into regs, hi/lo bf16 split in-register (no A LDS);
// B (pre-tiled tern(w1)) double-buffered in LDS, ONE barrier per chunk; B(c+1) global->reg issued
// after the barrier, committed by ds_write at the top of chunk c+1 (latency hidden under 80 MFMAs).
// R6 FIX: chunk stride = 1280 uint4 (20480 B) for the unpadded [nt][quad][col][kk] layout —
// R5 reused R1's padded-layout constant 1600 and read garbage for chunks >= 1 (absmax 129).

#define TERN_TH 0.001f

using bf16x8 = __attribute__((ext_vector_type(8))) short;   // 8 bf16 = 4 VGPR
using f32x4  = __attribute__((ext_vector_type(4))) float;   // 4 fp32 acc

__device__ __forceinline__ unsigned short f2bf(float f) {
    unsigned u = __float_as_uint(f);
    u = (u + 0x7FFFu + ((u >> 16) & 1u)) >> 16;   // RNE
    return (unsigned short)u;
}
__device__ __forceinline__ float bf2f(unsigned short h) {
    return __uint_as_float(((unsigned)h) << 16);
}
__device__ __forceinline__ float ternf(float w) {
    return (w > TERN_TH) ? 1.0f : ((w < -TERN_TH) ? -1.0f : 0.0f);
}

__device__ __forceinline__ void split8(float4 a, float4 b, bf16x8& hi, bf16x8& lo) {
    float v[8] = {a.x, a.y, a.z, a.w, b.x, b.y, b.z, b.w};
    bf16x8 h, l;
#pragma unroll
    for (int i = 0; i < 8; ++i) {
        unsigned short hh = f2bf(v[i]);
        h[i] = (short)hh;
        l[i] = (short)f2bf(v[i] - bf2f(hh));
    }
    hi = h; lo = l;
}

// ---------------- prep: ternarize w1 -> bf16, B-fragment order:
// q1f[c(25)][nt(20)][quad(4)][col(16)][kk(8)]  (512000 B); chunk = 10240 bf16 = 20480 B = 1280 uint4
#define Q1F_ELEMS (25 * 20 * 4 * 16 * 8)
__global__ void prep_q1(const float* __restrict__ w1, unsigned short* __restrict__ q1f) {
    int idx = blockIdx.x * 256 + threadIdx.x;
    if (idx >= Q1F_ELEMS) return;
    int kk   = idx & 7;
    int col  = (idx >> 3) & 15;
    int quad = (idx >> 7) & 3;
    int t    = idx >> 9;
    int nt   = t % 20;
    int c    = t / 20;
    int k = c * 32 + quad * 8 + kk;
    int j = nt * 16 + col;
    float v = (k < 784) ? ternf(w1[j * 784 + k]) : 0.0f;
    q1f[idx] = f2bf(v);
}

// ---------------- LDS layout (bytes)
#define BCHUNK_U4 1280              // 20480 B per chunk  (FIX: was 1600)
#define LDS_BBUF(i) ((i) * 20480)   // buf0: 0..20480, buf1: 20480..40960
#define LDS_H   0                   // epilogue [64][328] bf16 = 41984 (B dead by then)
#define LDS_Q2  41984               // [16][328] bf16 = 10496 -> total 52480
#define LDS_TOTAL 52480

__global__ __launch_bounds__(256, 2) void mlp_main(
    const float* __restrict__ x, const unsigned short* __restrict__ q1f,
    const float* __restrict__ b1, const float* __restrict__ w2,
    const float* __restrict__ b2, float* __restrict__ out) {

    __shared__ __attribute__((aligned(16))) unsigned char smem[LDS_TOTAL];
    unsigned short* sm16 = (unsigned short*)smem;

    const int tid  = threadIdx.x;
    const int lane = tid & 63;
    const int wave = tid >> 6;     // 4 waves, each 32 rows x 320 cols
    const int quad = lane >> 4;
    const int l15  = lane & 15;
    const int blk  = blockIdx.x;   // 512 blocks * 128 rows

    f32x4 acc[2][20];
#pragma unroll
    for (int mt = 0; mt < 2; ++mt)
#pragma unroll
        for (int nt = 0; nt < 20; ++nt) {
            f32x4 z = {0.f, 0.f, 0.f, 0.f};
            acc[mt][nt] = z;
        }

    const int rowbase = blk * 128 + wave * 32;
    const float* xr0 = x + (size_t)(rowbase + l15) * 784;        // mt=0 row
    const float* xr1 = x + (size_t)(rowbase + 16 + l15) * 784;   // mt=1 row
    const uint4* bsrc = (const uint4*)q1f;

    uint4  br[5];       // B chunk staging regs (1280 uint4 / 256 thr = 5 each, exact)
    float4 xc[4];       // A raw floats, current chunk
    float4 xn[4];       // A raw floats, next chunk

    // ---- prologue: chunk 0 loads
    {
#pragma unroll
        for (int i = 0; i < 5; ++i) br[i] = bsrc[tid + i * 256];
        const float4* p0 = (const float4*)(xr0);   // c=0: kq = quad*8
        const float4* p1 = (const float4*)(xr1);
        xc[0] = p0[quad * 2]; xc[1] = p0[quad * 2 + 1];
        xc[2] = p1[quad * 2]; xc[3] = p1[quad * 2 + 1];
    }

    for (int c = 0; c < 25; ++c) {
        // ---- commit B chunk c to LDS buf[c&1] (vmcnt wait here is hidden by prev chunk's MFMAs)
        {
            uint4* dst = (uint4*)(smem + LDS_BBUF(c & 1));
#pragma unroll
            for (int i = 0; i < 5; ++i) dst[tid + i * 256] = br[i];
        }
        __syncthreads();

        // ---- issue next-chunk loads (consumed only at the top of the next iteration)
        if (c < 24) {
            int cn = c + 1;
            const uint4* src = bsrc + (size_t)cn * BCHUNK_U4;
#pragma unroll
            for (int i = 0; i < 5; ++i) br[i] = src[tid + i * 256];
            int kq  = cn * 32 + quad * 8;
            int kqs = (kq < 784) ? kq : 0;   // c==24, quad 2/3: B frag is zero there
            const float4* p0 = (const float4*)(xr0 + kqs);
            const float4* p1 = (const float4*)(xr1 + kqs);
            xn[0] = p0[0]; xn[1] = p0[1];
            xn[2] = p1[0]; xn[3] = p1[1];
        }

        // ---- split current A chunk in-register (VALU only, no memory wait)
        bf16x8 ahi0, alo0, ahi1, alo1;
        split8(xc[0], xc[1], ahi0, alo0);
        split8(xc[2], xc[3], ahi1, alo1);

        // ---- 20 x (ds_read b128 + 4 MFMA) from LDS buf[c&1]
        const unsigned char* bp = smem + LDS_BBUF(c & 1) + quad * 256 + l15 * 16;
#pragma unroll
        for (int nt = 0; nt < 20; ++nt) {
            bf16x8 bq = *(const bf16x8*)(bp + nt * 1024);
            acc[0][nt] = __builtin_amdgcn_mfma_f32_16x16x32_bf16(ahi0, bq, acc[0][nt], 0, 0, 0);
            acc[0][nt] = __builtin_amdgcn_mfma_f32_16x16x32_bf16(alo0, bq, acc[0][nt], 0, 0, 0);
            acc[1][nt] = __builtin_amdgcn_mfma_f32_16x16x32_bf16(ahi1, bq, acc[1][nt], 0, 0, 0);
            acc[1][nt] = __builtin_amdgcn_mfma_f32_16x16x32_bf16(alo1, bq, acc[1][nt], 0, 0, 0);
        }
#pragma unroll
        for (int i = 0; i < 4; ++i) xc[i] = xn[i];
    }

    // ---------------- fused epilogue (verified R4 structure)
    __syncthreads();
    for (int idx = tid; idx < 16 * 328; idx += 256) {
        int o = idx / 328, j = idx % 328;
        float v = (o < 10 && j < 320) ? ternf(w2[o * 320 + j]) : 0.0f;
        sm16[(LDS_Q2 >> 1) + idx] = f2bf(v);
    }
    float b1v[20];
#pragma unroll
    for (int nt = 0; nt < 20; ++nt) b1v[nt] = b1[nt * 16 + l15];
    float b2v = (l15 < 10) ? b2[l15] : 0.0f;

    for (int pass = 0; pass < 2; ++pass) {
        __syncthreads();
        if ((wave >> 1) == pass) {
#pragma unroll
            for (int mt = 0; mt < 2; ++mt)
#pragma unroll
                for (int nt = 0; nt < 20; ++nt)
#pragma unroll
                    for (int i = 0; i < 4; ++i) {
                        float hv = acc[mt][nt][i] + b1v[nt];
                        int row = (wave & 1) * 32 + mt * 16 + quad * 4 + i;  // C layout: col=lane&15, row=quad*4+reg
                        int col = nt * 16 + l15;
                        sm16[(LDS_H >> 1) + row * 328 + col] = f2bf(ternf(hv));
                    }
        }
        __syncthreads();
        f32x4 acc2 = {0.f, 0.f, 0.f, 0.f};
#pragma unroll
        for (int kc = 0; kc < 10; ++kc) {
            bf16x8 a = *(const bf16x8*)(smem + LDS_H + (wave * 16 + l15) * 656 + kc * 64 + quad * 16);
            bf16x8 b = *(const bf16x8*)(smem + LDS_Q2 + l15 * 656 + kc * 64 + quad * 16);
            acc2 = __builtin_amdgcn_mfma_f32_16x16x32_bf16(a, b, acc2, 0, 0, 0);
        }
#pragma unroll
        for (int i = 0; i < 4; ++i) {
            float l  = acc2[i] + b2v;
            float lm = (l15 < 10) ? l : -3.4e38f;
#pragma unroll
            for (int s = 8; s >= 1; s >>= 1) lm = fmaxf(lm, __shfl_xor(lm, s, 64));
            float e  = (l15 < 10) ? expf(l - lm) : 0.0f;
            float ss = e;
#pragma unroll
            for (int s = 8; s >= 1; s >>= 1) ss += __shfl_xor(ss, s, 64);
            float ov = (l - lm) - logf(ss);
            if (l15 < 10) {
                int grow = blk * 128 + pass * 64 + wave * 16 + quad * 4 + i;
                out[(size_t)grow * 10 + l15] = ov;
            }
        }
    }
}

extern "C" void kernel_launch(void* const* d_in, const int* in_sizes, int n_in,
                              void* d_out, int out_size, void* d_ws, size_t ws_size,
                              hipStream_t stream) {
    const float* x  = (const float*)d_in[0];
    const float* w1 = (const float*)d_in[1];
    const float* b1 = (const float*)d_in[2];
    const float* w2 = (const float*)d_in[3];
    const float* b2 = (const float*)d_in[4];
    unsigned short* q1f = (unsigned short*)d_ws;   // 512000 B

    prep_q1<<<(Q1F_ELEMS + 255) / 256, 256, 0, stream>>>(w1, q1f);
    mlp_main<<<512, 256, 0, stream>>>(x, q1f, b1, w2, b2, (float*)d_out);
}